// Round 1
// baseline (343.363 us; speedup 1.0000x reference)
//
#include <hip/hip_runtime.h>
#include <hip/hip_bf16.h>

// Fused attention block: S=2048, B=2, D=1024, H=16, HD=64.
// Round 1: correctness-first bf16-MFMA baseline.
//   d_in: X[2048,2,1024] f32, Wkv[1024,2048] f32, bkv[2048] f32,
//         Wq[1024,1024] f32, bq[1024] f32, Wp[1024,1024] f32, bp[1024] f32
//   d_out: [2048,2,1024] f32

typedef __bf16 bf16_t;
typedef __bf16 bf16x8 __attribute__((ext_vector_type(8)));
typedef float f32x4 __attribute__((ext_vector_type(4)));

#define S_LEN 2048
#define BATCH 2
#define DMODEL 1024
#define NHEAD 16
#define HDIM 64
#define ATT_SCALE 0.125f

// ---------------------------------------------------------------------------
// Transpose + convert: in f32 [K][N] -> out bf16 [N][K]
// ---------------------------------------------------------------------------
__global__ __launch_bounds__(256) void transpose_convert(
    const float* __restrict__ in, bf16_t* __restrict__ out, int K, int N)
{
    __shared__ float tile[64][65];
    int n0 = blockIdx.x * 64, k0 = blockIdx.y * 64;
    int r = threadIdx.x >> 2;        // 0..63
    int c = (threadIdx.x & 3) * 16;  // 0,16,32,48
    const float* src = in + (size_t)(k0 + r) * N + n0 + c;
#pragma unroll
    for (int j = 0; j < 16; j += 4) {
        float4 f = *(const float4*)(src + j);
        tile[r][c + j + 0] = f.x;
        tile[r][c + j + 1] = f.y;
        tile[r][c + j + 2] = f.z;
        tile[r][c + j + 3] = f.w;
    }
    __syncthreads();
    bf16x8 o0, o1;
#pragma unroll
    for (int j = 0; j < 8; ++j) o0[j] = (bf16_t)tile[c + j][r];
#pragma unroll
    for (int j = 0; j < 8; ++j) o1[j] = (bf16_t)tile[c + 8 + j][r];
    bf16_t* dst = out + (size_t)(n0 + r) * K + k0 + c;
    *(bf16x8*)dst = o0;
    *(bf16x8*)(dst + 8) = o1;
}

// ---------------------------------------------------------------------------
// GEMM: C[M,N] = A[M,K](f32, cvt->bf16) @ W[K,N] (via WT bf16 [N][K]) + bias
// MODE 0: N=2048, cols<1024 -> K-scatter, cols>=1024 -> V-scatter (bf16)
// MODE 1: Q-scatter with ATT_SCALE folded (bf16)
// MODE 2: plain f32 row-major out (final projection)
// Scatter layout for Q/K/V: [b*16+h][s][d] (bf16), s-major within head.
// 128x128 tile, BK=32, 4 waves (2x2 of 64x64), mfma_f32_16x16x32_bf16.
// ---------------------------------------------------------------------------
__device__ inline void cvt16(const float* __restrict__ src, bf16x8& a, bf16x8& b)
{
    float4 f0 = *(const float4*)(src + 0);
    float4 f1 = *(const float4*)(src + 4);
    float4 f2 = *(const float4*)(src + 8);
    float4 f3 = *(const float4*)(src + 12);
    a[0] = (bf16_t)f0.x; a[1] = (bf16_t)f0.y; a[2] = (bf16_t)f0.z; a[3] = (bf16_t)f0.w;
    a[4] = (bf16_t)f1.x; a[5] = (bf16_t)f1.y; a[6] = (bf16_t)f1.z; a[7] = (bf16_t)f1.w;
    b[0] = (bf16_t)f2.x; b[1] = (bf16_t)f2.y; b[2] = (bf16_t)f2.z; b[3] = (bf16_t)f2.w;
    b[4] = (bf16_t)f3.x; b[5] = (bf16_t)f3.y; b[6] = (bf16_t)f3.z; b[7] = (bf16_t)f3.w;
}

template <int MODE>
__global__ __launch_bounds__(256) void gemm_kernel(
    const float* __restrict__ A, const bf16_t* __restrict__ WT,
    const float* __restrict__ bias, int M, int N, int K,
    bf16_t* __restrict__ outK, bf16_t* __restrict__ outV,
    float* __restrict__ outF)
{
    __shared__ bf16_t As[128][40];  // [m][k], +8 pad keeps rows 16B aligned
    __shared__ bf16_t Bs[128][40];  // [n][k]
    int tid = threadIdx.x;
    int wave = tid >> 6, lane = tid & 63;
    int l15 = lane & 15, l4 = lane >> 4;
    int m0 = blockIdx.x * 128, n0 = blockIdx.y * 128;
    int wr = (wave >> 1) * 64, wc = (wave & 1) * 64;

    f32x4 acc[4][4] = {};

    int srow = tid >> 1;             // 0..127
    int sh = (tid & 1) * 16;         // 0 or 16 (k-half)

    for (int k0 = 0; k0 < K; k0 += 32) {
        __syncthreads();  // WAR on LDS tiles
        {   // stage A: 128 x 32, f32 -> bf16
            const float* src = A + (size_t)(m0 + srow) * K + k0 + sh;
            bf16x8 a, b;
            cvt16(src, a, b);
            *(bf16x8*)&As[srow][sh] = a;
            *(bf16x8*)&As[srow][sh + 8] = b;
        }
        {   // stage B: 128 n-rows x 32 k from WT (already bf16, contiguous)
            const bf16_t* src = WT + (size_t)(n0 + srow) * K + k0 + sh;
            bf16x8 a = *(const bf16x8*)src;
            bf16x8 b = *(const bf16x8*)(src + 8);
            *(bf16x8*)&Bs[srow][sh] = a;
            *(bf16x8*)&Bs[srow][sh + 8] = b;
        }
        __syncthreads();
        bf16x8 af[4], bfr[4];
#pragma unroll
        for (int i = 0; i < 4; ++i)
            af[i] = *(const bf16x8*)&As[wr + i * 16 + l15][l4 * 8];
#pragma unroll
        for (int i = 0; i < 4; ++i)
            bfr[i] = *(const bf16x8*)&Bs[wc + i * 16 + l15][l4 * 8];
#pragma unroll
        for (int mi = 0; mi < 4; ++mi)
#pragma unroll
            for (int ni = 0; ni < 4; ++ni)
                acc[mi][ni] = __builtin_amdgcn_mfma_f32_16x16x32_bf16(
                    af[mi], bfr[ni], acc[mi][ni], 0, 0, 0);
    }

    // epilogue: C/D layout col = lane&15, row = (lane>>4)*4 + e
#pragma unroll
    for (int mi = 0; mi < 4; ++mi) {
#pragma unroll
        for (int ni = 0; ni < 4; ++ni) {
#pragma unroll
            for (int e = 0; e < 4; ++e) {
                int gm = m0 + wr + mi * 16 + l4 * 4 + e;
                int gn = n0 + wc + ni * 16 + l15;
                float v = acc[mi][ni][e] + bias[gn];
                if (MODE == 0) {
                    int s = gm >> 1, b = gm & 1;
                    int nn = gn & 1023;
                    int h = nn >> 6, d = nn & 63;
                    bf16_t* dst = (gn < 1024) ? outK : outV;
                    dst[((size_t)((b << 4) + h) * S_LEN + s) * HDIM + d] = (bf16_t)v;
                } else if (MODE == 1) {
                    int s = gm >> 1, b = gm & 1;
                    int h = gn >> 6, d = gn & 63;
                    outK[((size_t)((b << 4) + h) * S_LEN + s) * HDIM + d] =
                        (bf16_t)(v * ATT_SCALE);
                } else {
                    outF[(size_t)gm * N + gn] = v;
                }
            }
        }
    }
}

// ---------------------------------------------------------------------------
// Flash attention: per (b,h): Q[S,64] (pre-scaled), K[S,64], V[S,64] bf16
// -> AVf f32 [4096][1024] (row m = s*B+b, col h*64+d)
// Block: 256 threads = 4 waves, each wave owns 16 q-rows (QBLK=64/block).
// K/V tiles of 32 rows staged in LDS; V transposed for the PV B-operand.
// Online softmax entirely wave-parallel (shfl_xor width 16).
// ---------------------------------------------------------------------------
__global__ __launch_bounds__(256) void flash_kernel(
    const bf16_t* __restrict__ Qb, const bf16_t* __restrict__ Kb,
    const bf16_t* __restrict__ Vb, float* __restrict__ AVf)
{
    __shared__ bf16_t Ks[32][72];       // [t][d]  (+8 pad, rows 144B = 16B-aligned)
    __shared__ bf16_t Vs[64][40];       // [d][t]  transposed
    __shared__ bf16_t Ps[4][16][40];    // per-wave P tile [q][t]

    int bh = blockIdx.y;                // b*16 + h
    int qblk = blockIdx.x;
    int tid = threadIdx.x, wave = tid >> 6, lane = tid & 63;
    int l15 = lane & 15, l4 = lane >> 4;

    const bf16_t* Qp = Qb + (size_t)bh * S_LEN * HDIM;
    const bf16_t* Kp = Kb + (size_t)bh * S_LEN * HDIM;
    const bf16_t* Vp = Vb + (size_t)bh * S_LEN * HDIM;

    int q0 = qblk * 64 + wave * 16;

    // Q fragments (A-operand): row = lane&15, k(d) = kb*32 + (lane>>4)*8 + j
    bf16x8 qf[2];
    qf[0] = *(const bf16x8*)(Qp + (size_t)(q0 + l15) * HDIM + 0 + l4 * 8);
    qf[1] = *(const bf16x8*)(Qp + (size_t)(q0 + l15) * HDIM + 32 + l4 * 8);

    f32x4 acc[4] = {};                  // O tile: 4 d-blocks of 16 cols
    float mrow[4], lrow[4];
#pragma unroll
    for (int e = 0; e < 4; ++e) { mrow[e] = -1e30f; lrow[e] = 0.f; }

    int srow = tid >> 3;                // 0..31 (t row)
    int scb = (tid & 7) * 8;            // 0..56 (d col block)

    for (int t0 = 0; t0 < S_LEN; t0 += 32) {
        __syncthreads();  // WAR: previous iteration done with Ks/Vs
        {   // stage K tile [32][64] and V tile transposed [64][32]
            bf16x8 kv = *(const bf16x8*)(Kp + (size_t)(t0 + srow) * HDIM + scb);
            *(bf16x8*)&Ks[srow][scb] = kv;
            bf16x8 vv = *(const bf16x8*)(Vp + (size_t)(t0 + srow) * HDIM + scb);
#pragma unroll
            for (int j = 0; j < 8; ++j) Vs[scb + j][srow] = vv[j];
        }
        __syncthreads();

        // scores: S[q][t] for 16 q x 32 t; D rows = q = 4*l4+e, cols = t = th*16+l15
        f32x4 sc0 = {}, sc1 = {};
        {
            bf16x8 k00 = *(const bf16x8*)&Ks[l15][l4 * 8];
            bf16x8 k01 = *(const bf16x8*)&Ks[l15][32 + l4 * 8];
            sc0 = __builtin_amdgcn_mfma_f32_16x16x32_bf16(qf[0], k00, sc0, 0, 0, 0);
            sc0 = __builtin_amdgcn_mfma_f32_16x16x32_bf16(qf[1], k01, sc0, 0, 0, 0);
            bf16x8 k10 = *(const bf16x8*)&Ks[16 + l15][l4 * 8];
            bf16x8 k11 = *(const bf16x8*)&Ks[16 + l15][32 + l4 * 8];
            sc1 = __builtin_amdgcn_mfma_f32_16x16x32_bf16(qf[0], k10, sc1, 0, 0, 0);
            sc1 = __builtin_amdgcn_mfma_f32_16x16x32_bf16(qf[1], k11, sc1, 0, 0, 0);
        }

        // online softmax per q-row (rows live across 16 lanes of a group)
        float p0[4], p1[4], scale[4];
#pragma unroll
        for (int e = 0; e < 4; ++e) {
            float pm = fmaxf(sc0[e], sc1[e]);
#pragma unroll
            for (int off = 1; off < 16; off <<= 1)
                pm = fmaxf(pm, __shfl_xor(pm, off, 16));
            float mn = fmaxf(mrow[e], pm);
            scale[e] = __expf(mrow[e] - mn);
            mrow[e] = mn;
            p0[e] = __expf(sc0[e] - mn);
            p1[e] = __expf(sc1[e] - mn);
            float rs = p0[e] + p1[e];
#pragma unroll
            for (int off = 1; off < 16; off <<= 1)
                rs += __shfl_xor(rs, off, 16);
            lrow[e] = lrow[e] * scale[e] + rs;
        }
#pragma unroll
        for (int db = 0; db < 4; ++db)
#pragma unroll
            for (int e = 0; e < 4; ++e) acc[db][e] *= scale[e];

        // P (D-layout) -> LDS -> A-fragment layout
#pragma unroll
        for (int e = 0; e < 4; ++e) {
            Ps[wave][4 * l4 + e][l15] = (bf16_t)p0[e];
            Ps[wave][4 * l4 + e][l15 + 16] = (bf16_t)p1[e];
        }
        __syncthreads();
        bf16x8 pf = *(const bf16x8*)&Ps[wave][l15][l4 * 8];
#pragma unroll
        for (int db = 0; db < 4; ++db) {
            bf16x8 vf = *(const bf16x8*)&Vs[db * 16 + l15][l4 * 8];
            acc[db] = __builtin_amdgcn_mfma_f32_16x16x32_bf16(pf, vf, acc[db], 0, 0, 0);
        }
    }

    // epilogue: normalize and write AV (f32) rows m = s*B+b, cols h*64+d
    int b = bh >> 4, h = bh & 15;
#pragma unroll
    for (int db = 0; db < 4; ++db) {
#pragma unroll
        for (int e = 0; e < 4; ++e) {
            int s = q0 + 4 * l4 + e;
            int m = s * BATCH + b;
            AVf[(size_t)m * DMODEL + h * HDIM + db * 16 + l15] = acc[db][e] / lrow[e];
        }
    }
}

// ---------------------------------------------------------------------------
extern "C" void kernel_launch(void* const* d_in, const int* in_sizes, int n_in,
                              void* d_out, int out_size, void* d_ws, size_t ws_size,
                              hipStream_t stream)
{
    const float* X   = (const float*)d_in[0];
    const float* Wkv = (const float*)d_in[1];
    const float* bkv = (const float*)d_in[2];
    const float* Wq  = (const float*)d_in[3];
    const float* bq  = (const float*)d_in[4];
    const float* Wp  = (const float*)d_in[5];
    const float* bp  = (const float*)d_in[6];
    float* out = (float*)d_out;

    char* ws = (char*)d_ws;
    size_t off = 0;
    auto alloc = [&](size_t bytes) -> void* {
        void* p = ws + off;
        off += (bytes + 255) & ~(size_t)255;
        return p;
    };
    bf16_t* WkvT = (bf16_t*)alloc((size_t)2048 * 1024 * 2);
    bf16_t* WqT  = (bf16_t*)alloc((size_t)1024 * 1024 * 2);
    bf16_t* WpT  = (bf16_t*)alloc((size_t)1024 * 1024 * 2);
    bf16_t* Qb   = (bf16_t*)alloc((size_t)32 * S_LEN * HDIM * 2);
    bf16_t* Kb   = (bf16_t*)alloc((size_t)32 * S_LEN * HDIM * 2);
    bf16_t* Vb   = (bf16_t*)alloc((size_t)32 * S_LEN * HDIM * 2);
    float*  AVf  = (float*)alloc((size_t)4096 * 1024 * 4);

    // weight transposes (bf16 [N][K])
    transpose_convert<<<dim3(32, 16), 256, 0, stream>>>(Wkv, WkvT, 1024, 2048);
    transpose_convert<<<dim3(16, 16), 256, 0, stream>>>(Wq, WqT, 1024, 1024);
    transpose_convert<<<dim3(16, 16), 256, 0, stream>>>(Wp, WpT, 1024, 1024);

    // projections: M=4096
    gemm_kernel<0><<<dim3(32, 16), 256, 0, stream>>>(X, WkvT, bkv, 4096, 2048, 1024,
                                                     Kb, Vb, nullptr);
    gemm_kernel<1><<<dim3(32, 8), 256, 0, stream>>>(X, WqT, bq, 4096, 1024, 1024,
                                                    Qb, nullptr, nullptr);
    // attention
    flash_kernel<<<dim3(S_LEN / 64, 32), 256, 0, stream>>>(Qb, Kb, Vb, AVf);

    // output projection
    gemm_kernel<2><<<dim3(32, 8), 256, 0, stream>>>(AVf, WpT, bp, 4096, 1024, 1024,
                                                    nullptr, nullptr, out);
}

// Round 2
// 261.324 us; speedup vs baseline: 1.3139x; 1.3139x over previous
//
#include <hip/hip_runtime.h>
#include <hip/hip_bf16.h>

// Fused attention block: S=2048, B=2, D=1024, H=16, HD=64.
// Round 2: flash kernel rewrite — KVBLK=64, double-buffered reg-staged K/V,
// conflict-free LDS strides (72), 1 barrier/iter, exp2-based softmax, setprio.

typedef __bf16 bf16_t;
typedef __bf16 bf16x8 __attribute__((ext_vector_type(8)));
typedef __bf16 bf16x4 __attribute__((ext_vector_type(4)));
typedef __bf16 bf16x2 __attribute__((ext_vector_type(2)));
typedef float f32x4 __attribute__((ext_vector_type(4)));

#define S_LEN 2048
#define BATCH 2
#define DMODEL 1024
#define NHEAD 16
#define HDIM 64
#define KVB 64
#define NT (S_LEN / KVB)
// 0.125 (1/sqrt(64)) * log2(e), folded into Q so softmax can use exp2
#define Q_SCALE 0.1803368801111204f

// ---------------------------------------------------------------------------
// Transpose + convert: in f32 [K][N] -> out bf16 [N][K]
// ---------------------------------------------------------------------------
__global__ __launch_bounds__(256) void transpose_convert(
    const float* __restrict__ in, bf16_t* __restrict__ out, int K, int N)
{
    __shared__ float tile[64][65];
    int n0 = blockIdx.x * 64, k0 = blockIdx.y * 64;
    int r = threadIdx.x >> 2;        // 0..63
    int c = (threadIdx.x & 3) * 16;  // 0,16,32,48
    const float* src = in + (size_t)(k0 + r) * N + n0 + c;
#pragma unroll
    for (int j = 0; j < 16; j += 4) {
        float4 f = *(const float4*)(src + j);
        tile[r][c + j + 0] = f.x;
        tile[r][c + j + 1] = f.y;
        tile[r][c + j + 2] = f.z;
        tile[r][c + j + 3] = f.w;
    }
    __syncthreads();
    bf16x8 o0, o1;
#pragma unroll
    for (int j = 0; j < 8; ++j) o0[j] = (bf16_t)tile[c + j][r];
#pragma unroll
    for (int j = 0; j < 8; ++j) o1[j] = (bf16_t)tile[c + 8 + j][r];
    bf16_t* dst = out + (size_t)(n0 + r) * K + k0 + c;
    *(bf16x8*)dst = o0;
    *(bf16x8*)(dst + 8) = o1;
}

// ---------------------------------------------------------------------------
// GEMM: C[M,N] = A[M,K](f32, cvt->bf16) @ W[K,N] (via WT bf16 [N][K]) + bias
// MODE 0: N=2048, cols<1024 -> K-scatter, cols>=1024 -> V-scatter (bf16)
// MODE 1: Q-scatter with Q_SCALE folded (bf16)
// MODE 2: plain f32 row-major out (final projection)
// ---------------------------------------------------------------------------
__device__ inline void cvt16(const float* __restrict__ src, bf16x8& a, bf16x8& b)
{
    float4 f0 = *(const float4*)(src + 0);
    float4 f1 = *(const float4*)(src + 4);
    float4 f2 = *(const float4*)(src + 8);
    float4 f3 = *(const float4*)(src + 12);
    a[0] = (bf16_t)f0.x; a[1] = (bf16_t)f0.y; a[2] = (bf16_t)f0.z; a[3] = (bf16_t)f0.w;
    a[4] = (bf16_t)f1.x; a[5] = (bf16_t)f1.y; a[6] = (bf16_t)f1.z; a[7] = (bf16_t)f1.w;
    b[0] = (bf16_t)f2.x; b[1] = (bf16_t)f2.y; b[2] = (bf16_t)f2.z; b[3] = (bf16_t)f2.w;
    b[4] = (bf16_t)f3.x; b[5] = (bf16_t)f3.y; b[6] = (bf16_t)f3.z; b[7] = (bf16_t)f3.w;
}

template <int MODE>
__global__ __launch_bounds__(256) void gemm_kernel(
    const float* __restrict__ A, const bf16_t* __restrict__ WT,
    const float* __restrict__ bias, int M, int N, int K,
    bf16_t* __restrict__ outK, bf16_t* __restrict__ outV,
    float* __restrict__ outF)
{
    __shared__ bf16_t As[128][40];
    __shared__ bf16_t Bs[128][40];
    int tid = threadIdx.x;
    int wave = tid >> 6, lane = tid & 63;
    int l15 = lane & 15, l4 = lane >> 4;
    int m0 = blockIdx.x * 128, n0 = blockIdx.y * 128;
    int wr = (wave >> 1) * 64, wc = (wave & 1) * 64;

    f32x4 acc[4][4] = {};

    int srow = tid >> 1;
    int sh = (tid & 1) * 16;

    for (int k0 = 0; k0 < K; k0 += 32) {
        __syncthreads();
        {
            const float* src = A + (size_t)(m0 + srow) * K + k0 + sh;
            bf16x8 a, b;
            cvt16(src, a, b);
            *(bf16x8*)&As[srow][sh] = a;
            *(bf16x8*)&As[srow][sh + 8] = b;
        }
        {
            const bf16_t* src = WT + (size_t)(n0 + srow) * K + k0 + sh;
            bf16x8 a = *(const bf16x8*)src;
            bf16x8 b = *(const bf16x8*)(src + 8);
            *(bf16x8*)&Bs[srow][sh] = a;
            *(bf16x8*)&Bs[srow][sh + 8] = b;
        }
        __syncthreads();
        bf16x8 af[4], bfr[4];
#pragma unroll
        for (int i = 0; i < 4; ++i)
            af[i] = *(const bf16x8*)&As[wr + i * 16 + l15][l4 * 8];
#pragma unroll
        for (int i = 0; i < 4; ++i)
            bfr[i] = *(const bf16x8*)&Bs[wc + i * 16 + l15][l4 * 8];
#pragma unroll
        for (int mi = 0; mi < 4; ++mi)
#pragma unroll
            for (int ni = 0; ni < 4; ++ni)
                acc[mi][ni] = __builtin_amdgcn_mfma_f32_16x16x32_bf16(
                    af[mi], bfr[ni], acc[mi][ni], 0, 0, 0);
    }

#pragma unroll
    for (int mi = 0; mi < 4; ++mi) {
#pragma unroll
        for (int ni = 0; ni < 4; ++ni) {
#pragma unroll
            for (int e = 0; e < 4; ++e) {
                int gm = m0 + wr + mi * 16 + l4 * 4 + e;
                int gn = n0 + wc + ni * 16 + l15;
                float v = acc[mi][ni][e] + bias[gn];
                if (MODE == 0) {
                    int s = gm >> 1, b = gm & 1;
                    int nn = gn & 1023;
                    int h = nn >> 6, d = nn & 63;
                    bf16_t* dst = (gn < 1024) ? outK : outV;
                    dst[((size_t)((b << 4) + h) * S_LEN + s) * HDIM + d] = (bf16_t)v;
                } else if (MODE == 1) {
                    int s = gm >> 1, b = gm & 1;
                    int h = gn >> 6, d = gn & 63;
                    outK[((size_t)((b << 4) + h) * S_LEN + s) * HDIM + d] =
                        (bf16_t)(v * Q_SCALE);
                } else {
                    outF[(size_t)gm * N + gn] = v;
                }
            }
        }
    }
}

// ---------------------------------------------------------------------------
// Flash attention. Per (b,h): Q (pre-scaled by Q_SCALE), K, V all [S,64] bf16.
// Block = 4 waves, wave owns 16 q-rows (QBLK=64). KVBLK=64, double-buffered,
// reg-staged prefetch (loads issued before compute, LDS writes after).
// One __syncthreads per KV tile. All LDS strides 72 (conflict-free for both
// b128 fragment reads and the staging writes). V staged transposed [d][t]
// via paired-bf16 b32 writes with a lane mapping giving 2-way (free) banking.
// ---------------------------------------------------------------------------
__global__ __launch_bounds__(256) void flash_kernel(
    const bf16_t* __restrict__ Qb, const bf16_t* __restrict__ Kb,
    const bf16_t* __restrict__ Vb, float* __restrict__ AVf)
{
    __shared__ bf16_t Ks[2][KVB][72];    // [t][d]
    __shared__ bf16_t Vs[2][HDIM][72];   // [d][t]
    __shared__ bf16_t Ps[4][16][72];     // per-wave P [q][t]

    int bh = blockIdx.y;
    int tid = threadIdx.x, wave = tid >> 6, lane = tid & 63;
    int l15 = lane & 15, l4 = lane >> 4;

    const bf16_t* Qp = Qb + (size_t)bh * S_LEN * HDIM;
    const bf16_t* Kp = Kb + (size_t)bh * S_LEN * HDIM;
    const bf16_t* Vp = Vb + (size_t)bh * S_LEN * HDIM;

    int q0 = blockIdx.x * 64 + wave * 16;

    // Q fragments: A[row=l15][k = kh*32 + l4*8 + j]
    bf16x8 qf[2];
    qf[0] = *(const bf16x8*)(Qp + (size_t)(q0 + l15) * HDIM + l4 * 8);
    qf[1] = *(const bf16x8*)(Qp + (size_t)(q0 + l15) * HDIM + 32 + l4 * 8);

    f32x4 acc[4] = {};
    float mrow[4], lrow[4];
#pragma unroll
    for (int e = 0; e < 4; ++e) { mrow[e] = -1e30f; lrow[e] = 0.f; }

    // K staging map: row sr (+32), 16B col chunk sc
    int sr = tid >> 3;            // 0..31
    int sc = (tid & 7) * 8;       // 0..56
    // V staging map: d-group vd (4 cols), t-pair vt (2-way LDS write banking)
    int vd = (tid >> 4) * 4;      // 0..60
    int vt = (tid & 15) * 2;      // 0..30

    bf16x8 kreg[2];
    bf16x4 vreg[2][2];

    // ---- prologue: stage tile 0 into buffer 0
    {
        const bf16_t* kb = Kp + (size_t)sr * HDIM + sc;
        kreg[0] = *(const bf16x8*)kb;
        kreg[1] = *(const bf16x8*)(kb + 32 * HDIM);
        const bf16_t* vb = Vp + (size_t)vt * HDIM + vd;
        vreg[0][0] = *(const bf16x4*)vb;
        vreg[0][1] = *(const bf16x4*)(vb + HDIM);
        vreg[1][0] = *(const bf16x4*)(vb + 32 * HDIM);
        vreg[1][1] = *(const bf16x4*)(vb + 33 * HDIM);
        *(bf16x8*)&Ks[0][sr][sc] = kreg[0];
        *(bf16x8*)&Ks[0][sr + 32][sc] = kreg[1];
#pragma unroll
        for (int p = 0; p < 2; ++p)
#pragma unroll
            for (int j = 0; j < 4; ++j) {
                bf16x2 w;
                w[0] = vreg[p][0][j];
                w[1] = vreg[p][1][j];
                *(bf16x2*)&Vs[0][vd + j][vt + 32 * p] = w;
            }
    }

    for (int it = 0; it < NT; ++it) {
        int cur = it & 1;
        __syncthreads();   // buf[cur] visible; everyone done reading buf[cur^1]

        // issue next-tile global loads early (latency hides under compute)
        if (it + 1 < NT) {
            const bf16_t* kb = Kp + (size_t)((it + 1) * KVB + sr) * HDIM + sc;
            kreg[0] = *(const bf16x8*)kb;
            kreg[1] = *(const bf16x8*)(kb + 32 * HDIM);
            const bf16_t* vb = Vp + (size_t)((it + 1) * KVB + vt) * HDIM + vd;
            vreg[0][0] = *(const bf16x4*)vb;
            vreg[0][1] = *(const bf16x4*)(vb + HDIM);
            vreg[1][0] = *(const bf16x4*)(vb + 32 * HDIM);
            vreg[1][1] = *(const bf16x4*)(vb + 33 * HDIM);
        }

        // ---- QK^T: 4 t-tiles x 2 k-halves
        f32x4 s4[4] = {};
        __builtin_amdgcn_s_setprio(1);
#pragma unroll
        for (int kh = 0; kh < 2; ++kh)
#pragma unroll
            for (int ti = 0; ti < 4; ++ti) {
                bf16x8 kf = *(const bf16x8*)&Ks[cur][ti * 16 + l15][kh * 32 + l4 * 8];
                s4[ti] = __builtin_amdgcn_mfma_f32_16x16x32_bf16(
                    qf[kh], kf, s4[ti], 0, 0, 0);
            }
        __builtin_amdgcn_s_setprio(0);

        // ---- online softmax (scores already in log2 units)
        float scl[4];
#pragma unroll
        for (int e = 0; e < 4; ++e) {
            float pm = fmaxf(fmaxf(s4[0][e], s4[1][e]), fmaxf(s4[2][e], s4[3][e]));
#pragma unroll
            for (int off = 1; off < 16; off <<= 1)
                pm = fmaxf(pm, __shfl_xor(pm, off, 16));
            float mn = fmaxf(mrow[e], pm);
            scl[e] = exp2f(mrow[e] - mn);
            mrow[e] = mn;
            float rs = 0.f;
#pragma unroll
            for (int ti = 0; ti < 4; ++ti) {
                float p = exp2f(s4[ti][e] - mn);
                s4[ti][e] = p;
                rs += p;
            }
#pragma unroll
            for (int off = 1; off < 16; off <<= 1)
                rs += __shfl_xor(rs, off, 16);
            lrow[e] = lrow[e] * scl[e] + rs;
        }
#pragma unroll
        for (int db = 0; db < 4; ++db)
#pragma unroll
            for (int e = 0; e < 4; ++e) acc[db][e] *= scl[e];

        // ---- P: D-layout -> per-wave LDS -> A-fragment (no barrier needed)
#pragma unroll
        for (int ti = 0; ti < 4; ++ti)
#pragma unroll
            for (int e = 0; e < 4; ++e)
                Ps[wave][4 * l4 + e][ti * 16 + l15] = (bf16_t)s4[ti][e];

        bf16x8 pf0 = *(const bf16x8*)&Ps[wave][l15][l4 * 8];
        bf16x8 pf1 = *(const bf16x8*)&Ps[wave][l15][32 + l4 * 8];

        // ---- PV
        __builtin_amdgcn_s_setprio(1);
#pragma unroll
        for (int db = 0; db < 4; ++db) {
            bf16x8 v0 = *(const bf16x8*)&Vs[cur][db * 16 + l15][l4 * 8];
            bf16x8 v1 = *(const bf16x8*)&Vs[cur][db * 16 + l15][32 + l4 * 8];
            acc[db] = __builtin_amdgcn_mfma_f32_16x16x32_bf16(pf0, v0, acc[db], 0, 0, 0);
            acc[db] = __builtin_amdgcn_mfma_f32_16x16x32_bf16(pf1, v1, acc[db], 0, 0, 0);
        }
        __builtin_amdgcn_s_setprio(0);

        // ---- write prefetched tile into the other buffer (after compute)
        if (it + 1 < NT) {
            int nxt = cur ^ 1;
            *(bf16x8*)&Ks[nxt][sr][sc] = kreg[0];
            *(bf16x8*)&Ks[nxt][sr + 32][sc] = kreg[1];
#pragma unroll
            for (int p = 0; p < 2; ++p)
#pragma unroll
                for (int j = 0; j < 4; ++j) {
                    bf16x2 w;
                    w[0] = vreg[p][0][j];
                    w[1] = vreg[p][1][j];
                    *(bf16x2*)&Vs[nxt][vd + j][vt + 32 * p] = w;
                }
        }
    }

    // ---- epilogue: normalize, write AV f32 rows m = s*B+b, cols h*64+d
    int b = bh >> 4, h = bh & 15;
#pragma unroll
    for (int db = 0; db < 4; ++db) {
#pragma unroll
        for (int e = 0; e < 4; ++e) {
            int s = q0 + 4 * l4 + e;
            int m = s * BATCH + b;
            AVf[(size_t)m * DMODEL + h * HDIM + db * 16 + l15] = acc[db][e] / lrow[e];
        }
    }
}

// ---------------------------------------------------------------------------
extern "C" void kernel_launch(void* const* d_in, const int* in_sizes, int n_in,
                              void* d_out, int out_size, void* d_ws, size_t ws_size,
                              hipStream_t stream)
{
    const float* X   = (const float*)d_in[0];
    const float* Wkv = (const float*)d_in[1];
    const float* bkv = (const float*)d_in[2];
    const float* Wq  = (const float*)d_in[3];
    const float* bq  = (const float*)d_in[4];
    const float* Wp  = (const float*)d_in[5];
    const float* bp  = (const float*)d_in[6];
    float* out = (float*)d_out;

    char* ws = (char*)d_ws;
    size_t off = 0;
    auto alloc = [&](size_t bytes) -> void* {
        void* p = ws + off;
        off += (bytes + 255) & ~(size_t)255;
        return p;
    };
    bf16_t* WkvT = (bf16_t*)alloc((size_t)2048 * 1024 * 2);
    bf16_t* WqT  = (bf16_t*)alloc((size_t)1024 * 1024 * 2);
    bf16_t* WpT  = (bf16_t*)alloc((size_t)1024 * 1024 * 2);
    bf16_t* Qb   = (bf16_t*)alloc((size_t)32 * S_LEN * HDIM * 2);
    bf16_t* Kb   = (bf16_t*)alloc((size_t)32 * S_LEN * HDIM * 2);
    bf16_t* Vb   = (bf16_t*)alloc((size_t)32 * S_LEN * HDIM * 2);
    float*  AVf  = (float*)alloc((size_t)4096 * 1024 * 4);

    transpose_convert<<<dim3(32, 16), 256, 0, stream>>>(Wkv, WkvT, 1024, 2048);
    transpose_convert<<<dim3(16, 16), 256, 0, stream>>>(Wq, WqT, 1024, 1024);
    transpose_convert<<<dim3(16, 16), 256, 0, stream>>>(Wp, WpT, 1024, 1024);

    gemm_kernel<0><<<dim3(32, 16), 256, 0, stream>>>(X, WkvT, bkv, 4096, 2048, 1024,
                                                     Kb, Vb, nullptr);
    gemm_kernel<1><<<dim3(32, 8), 256, 0, stream>>>(X, WqT, bq, 4096, 1024, 1024,
                                                    Qb, nullptr, nullptr);
    flash_kernel<<<dim3(S_LEN / 64, 32), 256, 0, stream>>>(Qb, Kb, Vb, AVf);

    gemm_kernel<2><<<dim3(32, 8), 256, 0, stream>>>(AVf, WpT, bp, 4096, 1024, 1024,
                                                    nullptr, nullptr, out);
}

// Round 3
// 173.655 us; speedup vs baseline: 1.9773x; 1.5048x over previous
//
#include <hip/hip_runtime.h>
#include <hip/hip_bf16.h>
#include <stdint.h>

// Fused attention block: S=2048, B=2, D=1024, H=16, HD=64.
// Round 3: (a) flash rewritten to swapped-QK^T 32x32 MFMA structure
// (lane-local softmax, in-register P exchange, gload_lds K staging),
// (b) all GEMMs use global_load_lds width-16 staging (m97 recipe) on bf16.

typedef __bf16 bf16_t;
typedef __bf16 bf16x8 __attribute__((ext_vector_type(8)));
typedef __bf16 bf16x4 __attribute__((ext_vector_type(4)));
typedef __bf16 bf16x2 __attribute__((ext_vector_type(2)));
typedef float f32x4 __attribute__((ext_vector_type(4)));
typedef float f32x16 __attribute__((ext_vector_type(16)));
typedef uint32_t u32;

#define S_LEN 2048
#define BATCH 2
#define DMODEL 1024
#define NHEAD 16
#define HDIM 64
#define KVB 64
#define FNT (S_LEN / KVB)
// 0.125 (1/sqrt(64)) * log2(e), folded into Q so softmax uses exp2
#define Q_SCALE 0.1803368801111204f

__device__ inline void gld16(const void* g, void* l)
{
    __builtin_amdgcn_global_load_lds(
        (const __attribute__((address_space(1))) void*)g,
        (__attribute__((address_space(3))) void*)l, 16, 0, 0);
}

__device__ inline u32 pack2(float a, float b)
{
    union { bf16x2 h; u32 u; } c;
    c.h[0] = (bf16_t)a; c.h[1] = (bf16_t)b;
    return c.u;
}

// ---------------------------------------------------------------------------
// X f32 -> bf16 (row-major passthrough)
// ---------------------------------------------------------------------------
__global__ __launch_bounds__(256) void xcvt_kernel(
    const float* __restrict__ in, bf16_t* __restrict__ out)
{
    size_t i = ((size_t)blockIdx.x * 256 + threadIdx.x) * 8;
    float4 f0 = *(const float4*)(in + i);
    float4 f1 = *(const float4*)(in + i + 4);
    bf16x8 o;
    o[0] = (bf16_t)f0.x; o[1] = (bf16_t)f0.y; o[2] = (bf16_t)f0.z; o[3] = (bf16_t)f0.w;
    o[4] = (bf16_t)f1.x; o[5] = (bf16_t)f1.y; o[6] = (bf16_t)f1.z; o[7] = (bf16_t)f1.w;
    *(bf16x8*)(out + i) = o;
}

// ---------------------------------------------------------------------------
// Transpose + convert: in f32 [K][N] -> out bf16 [N][K]
// ---------------------------------------------------------------------------
__global__ __launch_bounds__(256) void transpose_convert(
    const float* __restrict__ in, bf16_t* __restrict__ out, int K, int N)
{
    __shared__ float tile[64][65];
    int n0 = blockIdx.x * 64, k0 = blockIdx.y * 64;
    int r = threadIdx.x >> 2;
    int c = (threadIdx.x & 3) * 16;
    const float* src = in + (size_t)(k0 + r) * N + n0 + c;
#pragma unroll
    for (int j = 0; j < 16; j += 4) {
        float4 f = *(const float4*)(src + j);
        tile[r][c + j + 0] = f.x;
        tile[r][c + j + 1] = f.y;
        tile[r][c + j + 2] = f.z;
        tile[r][c + j + 3] = f.w;
    }
    __syncthreads();
    bf16x8 o0, o1;
#pragma unroll
    for (int j = 0; j < 8; ++j) o0[j] = (bf16_t)tile[c + j][r];
#pragma unroll
    for (int j = 0; j < 8; ++j) o1[j] = (bf16_t)tile[c + 8 + j][r];
    bf16_t* dst = out + (size_t)(n0 + r) * K + k0 + c;
    *(bf16x8*)dst = o0;
    *(bf16x8*)(dst + 8) = o1;
}

// ---------------------------------------------------------------------------
// GEMM (m97 recipe): C[M,N] = A[M,K] bf16 @ W (via WT bf16 [N][K]) + bias
// 128x128 tile, BK=32, 4 waves, global_load_lds width-16 staging, linear LDS.
// MODE 0: K/V scatter; MODE 1: Q scatter (Q_SCALE folded); MODE 2: f32 out.
// ---------------------------------------------------------------------------
template <int MODE>
__global__ __launch_bounds__(256) void gemm_kernel(
    const bf16_t* __restrict__ A, const bf16_t* __restrict__ WT,
    const float* __restrict__ bias, int M, int N, int K,
    bf16_t* __restrict__ outK, bf16_t* __restrict__ outV,
    float* __restrict__ outF)
{
    __shared__ bf16_t As[128 * 32];
    __shared__ bf16_t Bs[128 * 32];
    int tid = threadIdx.x;
    int wave = tid >> 6, lane = tid & 63;
    int l15 = lane & 15, l4 = lane >> 4;
    int m0 = blockIdx.x * 128, n0 = blockIdx.y * 128;
    int wr = (wave >> 1) * 64, wc = (wave & 1) * 64;

    // staging assignment: wave 0/1 -> As halves, wave 2/3 -> Bs halves
    bf16_t* ldsT = (wave < 2) ? As : Bs;
    const bf16_t* gbase = (wave < 2) ? A : WT;
    int rbase = (wave & 1) * 64;
    int tile0 = (wave < 2) ? m0 : n0;
    int srow = lane >> 2;            // 0..15 within a 16-row chunk
    int scol = (lane & 3) * 8;       // elements

    f32x4 acc[4][4] = {};

    for (int k0 = 0; k0 < K; k0 += 32) {
#pragma unroll
        for (int j = 0; j < 4; ++j) {
            const bf16_t* g = gbase +
                (size_t)(tile0 + rbase + j * 16 + srow) * K + k0 + scol;
            gld16(g, ldsT + (rbase + j * 16) * 32);
        }
        __syncthreads();   // vmcnt(0) drain: staged data visible
        bf16x8 af[4], bfr[4];
#pragma unroll
        for (int i = 0; i < 4; ++i)
            af[i] = *(const bf16x8*)&As[(wr + i * 16 + l15) * 32 + l4 * 8];
#pragma unroll
        for (int i = 0; i < 4; ++i)
            bfr[i] = *(const bf16x8*)&Bs[(wc + i * 16 + l15) * 32 + l4 * 8];
#pragma unroll
        for (int mi = 0; mi < 4; ++mi)
#pragma unroll
            for (int ni = 0; ni < 4; ++ni)
                acc[mi][ni] = __builtin_amdgcn_mfma_f32_16x16x32_bf16(
                    af[mi], bfr[ni], acc[mi][ni], 0, 0, 0);
        __syncthreads();   // all reads done before next overwrite
    }

#pragma unroll
    for (int mi = 0; mi < 4; ++mi) {
#pragma unroll
        for (int ni = 0; ni < 4; ++ni) {
#pragma unroll
            for (int e = 0; e < 4; ++e) {
                int gm = m0 + wr + mi * 16 + l4 * 4 + e;
                int gn = n0 + wc + ni * 16 + l15;
                float v = acc[mi][ni][e] + bias[gn];
                if (MODE == 0) {
                    int s = gm >> 1, b = gm & 1;
                    int nn = gn & 1023;
                    int h = nn >> 6, d = nn & 63;
                    bf16_t* dst = (gn < 1024) ? outK : outV;
                    dst[((size_t)((b << 4) + h) * S_LEN + s) * HDIM + d] = (bf16_t)v;
                } else if (MODE == 1) {
                    int s = gm >> 1, b = gm & 1;
                    int h = gn >> 6, d = gn & 63;
                    outK[((size_t)((b << 4) + h) * S_LEN + s) * HDIM + d] =
                        (bf16_t)(v * Q_SCALE);
                } else {
                    outF[(size_t)gm * N + gn] = v;
                }
            }
        }
    }
}

// ---------------------------------------------------------------------------
// Flash attention, swapped-QK^T 32x32 structure.
// Block = 4 waves x QBLK=32 q-rows (128/block). Per KV tile (64 rows):
//   S^T = mfma32x32x16(K_frag, Q_frag)  -> lane owns P column q=lane&31
//   softmax lane-local (31 fmax + 1 shfl pair-combine)
//   P -> bf16 pack + shfl_xor(32) exchange -> PV B-fragments in-register
//   O^T += mfma32x32x16(V^T_frag, P_frag)  (cols=q: rescale lane-uniform)
// K staged via gload_lds with pre-swizzled source (XOR byte^=(t&7)<<4);
// V reg-staged transposed [d][t] stride 72. Double-buffered, 1 barrier/iter.
// ---------------------------------------------------------------------------
__global__ __launch_bounds__(256) void flash_kernel(
    const bf16_t* __restrict__ Qb, const bf16_t* __restrict__ Kb,
    const bf16_t* __restrict__ Vb, bf16_t* __restrict__ AVb)
{
    __shared__ __align__(16) char lds[34816];
    char* KsB = lds;                         // 2 x [64][64] bf16, swizzled
    bf16_t* VtB = (bf16_t*)(lds + 16384);    // 2 x [64][72] bf16

    int bh = blockIdx.y;
    int tid = threadIdx.x, wave = tid >> 6, lane = tid & 63;
    int l31 = lane & 31, hi = lane >> 5;

    const bf16_t* Qp = Qb + (size_t)bh * S_LEN * HDIM;
    const bf16_t* Kp = Kb + (size_t)bh * S_LEN * HDIM;
    const bf16_t* Vp = Vb + (size_t)bh * S_LEN * HDIM;

    int q0 = blockIdx.x * 128 + wave * 32;

    // Q fragments (B-operand): col=q=l31, k = dc*16 + hi*8 + j
    bf16x8 qf[4];
#pragma unroll
    for (int dc = 0; dc < 4; ++dc)
        qf[dc] = *(const bf16x8*)(Qp + (size_t)(q0 + l31) * HDIM + dc * 16 + hi * 8);

    f32x16 acc0 = {}, acc1 = {};   // O^T: rows d=crow(r,hi)(+32), col q=l31
    float m_run = -3e38f, l_run = 0.f;

    // K staging geometry (gload_lds): wave w stages rows w*16..w*16+15
    int krow = lane >> 3;                              // 0..7 within 8-row chunk
    int kcb = ((lane & 7) << 4) ^ (krow << 4);         // pre-swizzled col byte
    // V staging geometry (reg-staged transpose)
    int vd = (tid >> 4) * 4;   // 0..60
    int vt = (tid & 15) * 2;   // 0..30
    bf16x4 vreg[2][2];

    int swz = (l31 & 7) << 4;  // read-side XOR for K

#define STAGE_K(it, buf)                                                       \
    {                                                                          \
        _Pragma("unroll")                                                      \
        for (int j = 0; j < 2; ++j) {                                          \
            int t = wave * 16 + j * 8 + krow;                                  \
            const char* g = (const char*)Kp +                                  \
                ((size_t)((it) * KVB + t) * HDIM) * 2 + kcb;                   \
            gld16(g, KsB + (buf) * 8192 + (wave * 16 + j * 8) * 128);          \
        }                                                                      \
    }
#define LOAD_V(it)                                                             \
    {                                                                          \
        const bf16_t* vb = Vp + (size_t)((it) * KVB + vt) * HDIM + vd;         \
        vreg[0][0] = *(const bf16x4*)vb;                                       \
        vreg[0][1] = *(const bf16x4*)(vb + HDIM);                              \
        vreg[1][0] = *(const bf16x4*)(vb + 32 * HDIM);                         \
        vreg[1][1] = *(const bf16x4*)(vb + 33 * HDIM);                         \
    }
#define WRITE_V(buf)                                                           \
    {                                                                          \
        bf16_t* vtb = VtB + (buf) * 4608;                                      \
        _Pragma("unroll")                                                      \
        for (int p = 0; p < 2; ++p) {                                          \
            _Pragma("unroll")                                                  \
            for (int j = 0; j < 4; ++j) {                                      \
                bf16x2 w;                                                      \
                w[0] = vreg[p][0][j];                                          \
                w[1] = vreg[p][1][j];                                          \
                *(bf16x2*)&vtb[(vd + j) * 72 + vt + 32 * p] = w;               \
            }                                                                  \
        }                                                                      \
    }

    // prologue: tile 0 into buffer 0
    STAGE_K(0, 0);
    LOAD_V(0);
    WRITE_V(0);
    __syncthreads();

    for (int it = 0; it < FNT; ++it) {
        int cur = it & 1;
        if (it + 1 < FNT) {
            STAGE_K(it + 1, cur ^ 1);   // async into other buffer
            LOAD_V(it + 1);             // issue early, write after compute
        }

        // ---- QK^T (S^T): rows t, cols q
        f32x16 s0 = {}, s1 = {};
        __builtin_amdgcn_s_setprio(1);
#pragma unroll
        for (int dc = 0; dc < 4; ++dc) {
            bf16x8 k0 = *(const bf16x8*)(KsB + cur * 8192 + l31 * 128 +
                                         ((dc * 32 + hi * 16) ^ swz));
            bf16x8 k1 = *(const bf16x8*)(KsB + cur * 8192 + (32 + l31) * 128 +
                                         ((dc * 32 + hi * 16) ^ swz));
            s0 = __builtin_amdgcn_mfma_f32_32x32x16_bf16(k0, qf[dc], s0, 0, 0, 0);
            s1 = __builtin_amdgcn_mfma_f32_32x32x16_bf16(k1, qf[dc], s1, 0, 0, 0);
        }
        __builtin_amdgcn_s_setprio(0);

        // ---- softmax: lane-local over 32 regs + one pair-combine (lane^32)
        float pm = s0[0];
#pragma unroll
        for (int r = 1; r < 16; ++r) pm = fmaxf(pm, s0[r]);
#pragma unroll
        for (int r = 0; r < 16; ++r) pm = fmaxf(pm, s1[r]);
        pm = fmaxf(pm, __shfl_xor(pm, 32));
        float mn = fmaxf(m_run, pm);
        float scl = exp2f(m_run - mn);
        m_run = mn;
        float rs = 0.f;
#pragma unroll
        for (int r = 0; r < 16; ++r) { s0[r] = exp2f(s0[r] - mn); rs += s0[r]; }
#pragma unroll
        for (int r = 0; r < 16; ++r) { s1[r] = exp2f(s1[r] - mn); rs += s1[r]; }
        rs += __shfl_xor(rs, 32);
        l_run = l_run * scl + rs;
        acc0 *= scl;
        acc1 *= scl;

        // ---- P exchange + PV, per 16-t slot
        __builtin_amdgcn_s_setprio(1);
#pragma unroll
        for (int s = 0; s < 4; ++s) {
            const int base = 8 * (s & 1);
            f32x16& P = (s < 2) ? s0 : s1;
            u32 wA0 = pack2(P[base + 0], P[base + 1]);
            u32 wA1 = pack2(P[base + 2], P[base + 3]);
            u32 wB0 = pack2(P[base + 4], P[base + 5]);
            u32 wB1 = pack2(P[base + 6], P[base + 7]);
            u32 xA0 = __shfl_xor((int)wA0, 32);
            u32 xA1 = __shfl_xor((int)wA1, 32);
            u32 xB0 = __shfl_xor((int)wB0, 32);
            u32 xB1 = __shfl_xor((int)wB1, 32);
            union { u32 u[4]; bf16x8 v; } pa;
            pa.u[0] = hi ? xB0 : wA0;
            pa.u[1] = hi ? xB1 : wA1;
            pa.u[2] = hi ? wB0 : xA0;
            pa.u[3] = hi ? wB1 : xA1;
            const bf16_t* vtb = VtB + cur * 4608;
            bf16x8 va0 = *(const bf16x8*)&vtb[l31 * 72 + s * 16 + hi * 8];
            bf16x8 va1 = *(const bf16x8*)&vtb[(32 + l31) * 72 + s * 16 + hi * 8];
            acc0 = __builtin_amdgcn_mfma_f32_32x32x16_bf16(va0, pa.v, acc0, 0, 0, 0);
            acc1 = __builtin_amdgcn_mfma_f32_32x32x16_bf16(va1, pa.v, acc1, 0, 0, 0);
        }
        __builtin_amdgcn_s_setprio(0);

        if (it + 1 < FNT) WRITE_V(cur ^ 1);
        __syncthreads();   // drains vmcnt (K prefetch) + lgkm; flips buffers
    }

    // ---- epilogue: normalize, transpose via LDS scratch, coalesced write
    bf16_t* sw = (bf16_t*)lds + wave * (32 * 72);
    float inv = 1.0f / l_run;
#pragma unroll
    for (int g = 0; g < 4; ++g) {
        bf16x4 w0, w1;
#pragma unroll
        for (int e = 0; e < 4; ++e) {
            w0[e] = (bf16_t)(acc0[4 * g + e] * inv);
            w1[e] = (bf16_t)(acc1[4 * g + e] * inv);
        }
        int d0 = 8 * g + 4 * hi;
        *(bf16x4*)&sw[l31 * 72 + d0] = w0;
        *(bf16x4*)&sw[l31 * 72 + 32 + d0] = w1;
    }
    __syncthreads();
    {
        int q = lane >> 1, half = lane & 1;
        const bf16_t* srow = sw + q * 72 + half * 32;
        int s = q0 + q;
        int b = bh >> 4, h = bh & 15;
        bf16_t* dst = AVb + ((size_t)s * BATCH + b) * DMODEL + h * HDIM + half * 32;
#pragma unroll
        for (int k = 0; k < 4; ++k)
            *(bf16x8*)(dst + k * 8) = *(const bf16x8*)(srow + k * 8);
    }
}

// ---------------------------------------------------------------------------
extern "C" void kernel_launch(void* const* d_in, const int* in_sizes, int n_in,
                              void* d_out, int out_size, void* d_ws, size_t ws_size,
                              hipStream_t stream)
{
    const float* X   = (const float*)d_in[0];
    const float* Wkv = (const float*)d_in[1];
    const float* bkv = (const float*)d_in[2];
    const float* Wq  = (const float*)d_in[3];
    const float* bq  = (const float*)d_in[4];
    const float* Wp  = (const float*)d_in[5];
    const float* bp  = (const float*)d_in[6];
    float* out = (float*)d_out;

    char* ws = (char*)d_ws;
    size_t off = 0;
    auto alloc = [&](size_t bytes) -> void* {
        void* p = ws + off;
        off += (bytes + 255) & ~(size_t)255;
        return p;
    };
    bf16_t* WkvT = (bf16_t*)alloc((size_t)2048 * 1024 * 2);
    bf16_t* WqT  = (bf16_t*)alloc((size_t)1024 * 1024 * 2);
    bf16_t* WpT  = (bf16_t*)alloc((size_t)1024 * 1024 * 2);
    bf16_t* Qb   = (bf16_t*)alloc((size_t)32 * S_LEN * HDIM * 2);
    bf16_t* Kb   = (bf16_t*)alloc((size_t)32 * S_LEN * HDIM * 2);
    bf16_t* Vb   = (bf16_t*)alloc((size_t)32 * S_LEN * HDIM * 2);
    bf16_t* Xbf  = (bf16_t*)alloc((size_t)4096 * 1024 * 2);
    bf16_t* AVb  = (bf16_t*)alloc((size_t)4096 * 1024 * 2);

    xcvt_kernel<<<2048, 256, 0, stream>>>(X, Xbf);
    transpose_convert<<<dim3(32, 16), 256, 0, stream>>>(Wkv, WkvT, 1024, 2048);
    transpose_convert<<<dim3(16, 16), 256, 0, stream>>>(Wq, WqT, 1024, 1024);
    transpose_convert<<<dim3(16, 16), 256, 0, stream>>>(Wp, WpT, 1024, 1024);

    gemm_kernel<0><<<dim3(32, 16), 256, 0, stream>>>(Xbf, WkvT, bkv, 4096, 2048, 1024,
                                                     Kb, Vb, nullptr);
    gemm_kernel<1><<<dim3(32, 8), 256, 0, stream>>>(Xbf, WqT, bq, 4096, 1024, 1024,
                                                    Qb, nullptr, nullptr);
    flash_kernel<<<dim3(S_LEN / 128, 32), 256, 0, stream>>>(Qb, Kb, Vb, AVb);

    gemm_kernel<2><<<dim3(32, 8), 256, 0, stream>>>(AVb, WpT, bp, 4096, 1024, 1024,
                                                    nullptr, nullptr, out);
}

// Round 5
// 157.447 us; speedup vs baseline: 2.1808x; 1.1029x over previous
//
#include <hip/hip_runtime.h>
#include <hip/hip_bf16.h>
#include <stdint.h>

// Fused attention block: S=2048, B=2, D=1024, H=16, HD=64.
// Round 5: R4 with the scalar cross-half combines fixed (shfl_xor instead of
// same-value permlane32_swap, which regalloc coalesced into one register).

typedef __bf16 bf16_t;
typedef __bf16 bf16x8 __attribute__((ext_vector_type(8)));
typedef __bf16 bf16x4 __attribute__((ext_vector_type(4)));
typedef __bf16 bf16x2 __attribute__((ext_vector_type(2)));
typedef float f32x4 __attribute__((ext_vector_type(4)));
typedef float f32x16 __attribute__((ext_vector_type(16)));
typedef uint32_t u32;

#define S_LEN 2048
#define BATCH 2
#define DMODEL 1024
#define NHEAD 16
#define HDIM 64
#define KVB 64
#define FNT (S_LEN / KVB)
// 0.125 (1/sqrt(64)) * log2(e), folded into Q so softmax uses exp2
#define Q_SCALE 0.1803368801111204f

__device__ inline void gld16(const void* g, void* l)
{
    __builtin_amdgcn_global_load_lds(
        (const __attribute__((address_space(1))) void*)g,
        (__attribute__((address_space(3))) void*)l, 16, 0, 0);
}

__device__ inline u32 pack2(float a, float b)
{
    union { bf16x2 h; u32 u; } c;
    c.h[0] = (bf16_t)a; c.h[1] = (bf16_t)b;
    return c.u;
}

// ---------------------------------------------------------------------------
// X f32 -> bf16
// ---------------------------------------------------------------------------
__global__ __launch_bounds__(256) void xcvt_kernel(
    const float* __restrict__ in, bf16_t* __restrict__ out)
{
    size_t i = ((size_t)blockIdx.x * 256 + threadIdx.x) * 8;
    float4 f0 = *(const float4*)(in + i);
    float4 f1 = *(const float4*)(in + i + 4);
    bf16x8 o;
    o[0] = (bf16_t)f0.x; o[1] = (bf16_t)f0.y; o[2] = (bf16_t)f0.z; o[3] = (bf16_t)f0.w;
    o[4] = (bf16_t)f1.x; o[5] = (bf16_t)f1.y; o[6] = (bf16_t)f1.z; o[7] = (bf16_t)f1.w;
    *(bf16x8*)(out + i) = o;
}

// ---------------------------------------------------------------------------
// Transpose + convert: in f32 [K][N] -> out bf16 [N][K]
// ---------------------------------------------------------------------------
__global__ __launch_bounds__(256) void transpose_convert(
    const float* __restrict__ in, bf16_t* __restrict__ out, int K, int N)
{
    __shared__ float tile[64][65];
    int n0 = blockIdx.x * 64, k0 = blockIdx.y * 64;
    int r = threadIdx.x >> 2;
    int c = (threadIdx.x & 3) * 16;
    const float* src = in + (size_t)(k0 + r) * N + n0 + c;
#pragma unroll
    for (int j = 0; j < 16; j += 4) {
        float4 f = *(const float4*)(src + j);
        tile[r][c + j + 0] = f.x;
        tile[r][c + j + 1] = f.y;
        tile[r][c + j + 2] = f.z;
        tile[r][c + j + 3] = f.w;
    }
    __syncthreads();
    bf16x8 o0, o1;
#pragma unroll
    for (int j = 0; j < 8; ++j) o0[j] = (bf16_t)tile[c + j][r];
#pragma unroll
    for (int j = 0; j < 8; ++j) o1[j] = (bf16_t)tile[c + 8 + j][r];
    bf16_t* dst = out + (size_t)(n0 + r) * K + k0 + c;
    *(bf16x8*)dst = o0;
    *(bf16x8*)(dst + 8) = o1;
}

// ---------------------------------------------------------------------------
// Fused QKV GEMM: C[4096,3072] = Xbf @ [Wkv|Wq] + [bkv|bq], scattered to
// K/V/Q head-major bf16 buffers. 128x128 tile, BK=32, gload_lds staging.
// ---------------------------------------------------------------------------
__global__ __launch_bounds__(256) void gemm_qkv(
    const bf16_t* __restrict__ A, const bf16_t* __restrict__ WT,
    const float* __restrict__ bkv, const float* __restrict__ bq,
    bf16_t* __restrict__ outK, bf16_t* __restrict__ outV,
    bf16_t* __restrict__ outQ)
{
    const int K = 1024;
    __shared__ bf16_t As[128 * 32];
    __shared__ bf16_t Bs[128 * 32];
    int tid = threadIdx.x;
    int wave = tid >> 6, lane = tid & 63;
    int l15 = lane & 15, l4 = lane >> 4;
    int m0 = blockIdx.x * 128, n0 = blockIdx.y * 128;
    int wr = (wave >> 1) * 64, wc = (wave & 1) * 64;

    bf16_t* ldsT = (wave < 2) ? As : Bs;
    const bf16_t* gbase = (wave < 2) ? A : WT;
    int rbase = (wave & 1) * 64;
    int tile0 = (wave < 2) ? m0 : n0;
    int srow = lane >> 2;
    int scol = (lane & 3) * 8;

    f32x4 acc[4][4] = {};

    for (int k0 = 0; k0 < K; k0 += 32) {
#pragma unroll
        for (int j = 0; j < 4; ++j) {
            const bf16_t* g = gbase +
                (size_t)(tile0 + rbase + j * 16 + srow) * K + k0 + scol;
            gld16(g, ldsT + (rbase + j * 16) * 32);
        }
        __syncthreads();
        bf16x8 af[4], bfr[4];
#pragma unroll
        for (int i = 0; i < 4; ++i)
            af[i] = *(const bf16x8*)&As[(wr + i * 16 + l15) * 32 + l4 * 8];
#pragma unroll
        for (int i = 0; i < 4; ++i)
            bfr[i] = *(const bf16x8*)&Bs[(wc + i * 16 + l15) * 32 + l4 * 8];
#pragma unroll
        for (int mi = 0; mi < 4; ++mi)
#pragma unroll
            for (int ni = 0; ni < 4; ++ni)
                acc[mi][ni] = __builtin_amdgcn_mfma_f32_16x16x32_bf16(
                    af[mi], bfr[ni], acc[mi][ni], 0, 0, 0);
        __syncthreads();
    }

#pragma unroll
    for (int mi = 0; mi < 4; ++mi) {
#pragma unroll
        for (int ni = 0; ni < 4; ++ni) {
#pragma unroll
            for (int e = 0; e < 4; ++e) {
                int gm = m0 + wr + mi * 16 + l4 * 4 + e;
                int gn = n0 + wc + ni * 16 + l15;
                float bsel = (gn < 2048) ? bkv[gn] : bq[gn - 2048];
                float v = acc[mi][ni][e] + bsel;
                int s = gm >> 1, b = gm & 1;
                int nn = gn & 1023;
                int h = nn >> 6, d = nn & 63;
                size_t idx = ((size_t)((b << 4) + h) * S_LEN + s) * HDIM + d;
                if (gn < 1024)
                    outK[idx] = (bf16_t)v;
                else if (gn < 2048)
                    outV[idx] = (bf16_t)v;
                else
                    outQ[idx] = (bf16_t)(v * Q_SCALE);
            }
        }
    }
}

// ---------------------------------------------------------------------------
// Output projection GEMM: out[4096,1024] f32 = AVb @ Wp + bp.
// 64x128 tile, BK=32, gload_lds staging. Grid 64x8 = 512 blocks (2/CU).
// ---------------------------------------------------------------------------
__global__ __launch_bounds__(256) void gemm_out_kernel(
    const bf16_t* __restrict__ A, const bf16_t* __restrict__ WT,
    const float* __restrict__ bias, float* __restrict__ outF)
{
    const int K = 1024, N = 1024;
    __shared__ bf16_t As[64 * 32];
    __shared__ bf16_t Bs[128 * 32];
    int tid = threadIdx.x, wave = tid >> 6, lane = tid & 63;
    int l15 = lane & 15, l4 = lane >> 4;
    int m0 = blockIdx.x * 64, n0 = blockIdx.y * 128;
    int wc = wave * 32;
    int srow = lane >> 2, scol = (lane & 3) * 8;

    f32x4 acc[4][2] = {};

    for (int k0 = 0; k0 < K; k0 += 32) {
#pragma unroll
        for (int j = 0; j < 3; ++j) {
            int slot = wave * 3 + j;  // 0..11: 0-3 -> As, 4-11 -> Bs
            const bf16_t* g;
            bf16_t* l;
            if (slot < 4) {
                g = A + (size_t)(m0 + slot * 16 + srow) * K + k0 + scol;
                l = As + slot * 512;
            } else {
                g = WT + (size_t)(n0 + (slot - 4) * 16 + srow) * K + k0 + scol;
                l = Bs + (slot - 4) * 512;
            }
            gld16(g, l);
        }
        __syncthreads();
        bf16x8 af[4], bfr[2];
#pragma unroll
        for (int i = 0; i < 4; ++i)
            af[i] = *(const bf16x8*)&As[(i * 16 + l15) * 32 + l4 * 8];
#pragma unroll
        for (int i = 0; i < 2; ++i)
            bfr[i] = *(const bf16x8*)&Bs[(wc + i * 16 + l15) * 32 + l4 * 8];
#pragma unroll
        for (int mi = 0; mi < 4; ++mi)
#pragma unroll
            for (int ni = 0; ni < 2; ++ni)
                acc[mi][ni] = __builtin_amdgcn_mfma_f32_16x16x32_bf16(
                    af[mi], bfr[ni], acc[mi][ni], 0, 0, 0);
        __syncthreads();
    }

#pragma unroll
    for (int mi = 0; mi < 4; ++mi)
#pragma unroll
        for (int ni = 0; ni < 2; ++ni)
#pragma unroll
            for (int e = 0; e < 4; ++e) {
                int gm = m0 + mi * 16 + l4 * 4 + e;
                int gn = n0 + wc + ni * 16 + l15;
                outF[(size_t)gm * N + gn] = acc[mi][ni][e] + bias[gn];
            }
}

// ---------------------------------------------------------------------------
// Flash attention, swapped-QK^T 32x32 structure:
//  - exact defer-rescale (skip when max didn't grow — scl==1 exactly)
//  - v_permlane32_swap_b32 for P-exchange (operands are distinct defs -> safe)
//  - __shfl_xor(.,32) for the scalar m/l cross-half combines (same-value
//    operands MUST NOT go through a 2-register asm swap: regalloc coalesces)
// ---------------------------------------------------------------------------
__global__ __launch_bounds__(256) void flash_kernel(
    const bf16_t* __restrict__ Qb, const bf16_t* __restrict__ Kb,
    const bf16_t* __restrict__ Vb, bf16_t* __restrict__ AVb)
{
    __shared__ __align__(16) char lds[34816];
    char* KsB = lds;                         // 2 x [64][64] bf16, swizzled
    bf16_t* VtB = (bf16_t*)(lds + 16384);    // 2 x [64][72] bf16

    int bh = blockIdx.y;
    int tid = threadIdx.x, wave = tid >> 6, lane = tid & 63;
    int l31 = lane & 31, hi = lane >> 5;

    const bf16_t* Qp = Qb + (size_t)bh * S_LEN * HDIM;
    const bf16_t* Kp = Kb + (size_t)bh * S_LEN * HDIM;
    const bf16_t* Vp = Vb + (size_t)bh * S_LEN * HDIM;

    int q0 = blockIdx.x * 128 + wave * 32;

    bf16x8 qf[4];
#pragma unroll
    for (int dc = 0; dc < 4; ++dc)
        qf[dc] = *(const bf16x8*)(Qp + (size_t)(q0 + l31) * HDIM + dc * 16 + hi * 8);

    f32x16 acc0 = {}, acc1 = {};
    float m_run = -3e38f, l_run = 0.f;

    int krow = lane >> 3;
    int kcb = ((lane & 7) << 4) ^ (krow << 4);
    int vd = (tid >> 4) * 4;
    int vt = (tid & 15) * 2;
    bf16x4 vreg[2][2];
    int swz = (l31 & 7) << 4;

#define STAGE_K(it, buf)                                                       \
    {                                                                          \
        _Pragma("unroll")                                                      \
        for (int j = 0; j < 2; ++j) {                                          \
            int t = wave * 16 + j * 8 + krow;                                  \
            const char* g = (const char*)Kp +                                  \
                ((size_t)((it) * KVB + t) * HDIM) * 2 + kcb;                   \
            gld16(g, KsB + (buf) * 8192 + (wave * 16 + j * 8) * 128);          \
        }                                                                      \
    }
#define LOAD_V(it)                                                             \
    {                                                                          \
        const bf16_t* vb = Vp + (size_t)((it) * KVB + vt) * HDIM + vd;         \
        vreg[0][0] = *(const bf16x4*)vb;                                       \
        vreg[0][1] = *(const bf16x4*)(vb + HDIM);                              \
        vreg[1][0] = *(const bf16x4*)(vb + 32 * HDIM);                         \
        vreg[1][1] = *(const bf16x4*)(vb + 33 * HDIM);                         \
    }
#define WRITE_V(buf)                                                           \
    {                                                                          \
        bf16_t* vtb = VtB + (buf) * 4608;                                      \
        _Pragma("unroll")                                                      \
        for (int p = 0; p < 2; ++p) {                                          \
            _Pragma("unroll")                                                  \
            for (int j = 0; j < 4; ++j) {                                      \
                bf16x2 w;                                                      \
                w[0] = vreg[p][0][j];                                          \
                w[1] = vreg[p][1][j];                                          \
                *(bf16x2*)&vtb[(vd + j) * 72 + vt + 32 * p] = w;               \
            }                                                                  \
        }                                                                      \
    }

    STAGE_K(0, 0);
    LOAD_V(0);
    WRITE_V(0);
    __syncthreads();

    for (int it = 0; it < FNT; ++it) {
        int cur = it & 1;
        if (it + 1 < FNT) {
            STAGE_K(it + 1, cur ^ 1);
            LOAD_V(it + 1);
        }

        // ---- QK^T (S^T)
        f32x16 s0 = {}, s1 = {};
        __builtin_amdgcn_s_setprio(1);
#pragma unroll
        for (int dc = 0; dc < 4; ++dc) {
            bf16x8 k0 = *(const bf16x8*)(KsB + cur * 8192 + l31 * 128 +
                                         ((dc * 32 + hi * 16) ^ swz));
            bf16x8 k1 = *(const bf16x8*)(KsB + cur * 8192 + (32 + l31) * 128 +
                                         ((dc * 32 + hi * 16) ^ swz));
            s0 = __builtin_amdgcn_mfma_f32_32x32x16_bf16(k0, qf[dc], s0, 0, 0, 0);
            s1 = __builtin_amdgcn_mfma_f32_32x32x16_bf16(k1, qf[dc], s1, 0, 0, 0);
        }
        __builtin_amdgcn_s_setprio(0);

        // ---- tree max over the 32 lane-local scores
        float v8[8];
#pragma unroll
        for (int r = 0; r < 8; ++r)
            v8[r] = fmaxf(fmaxf(s0[r], s0[r + 8]), fmaxf(s1[r], s1[r + 8]));
        float pm = fmaxf(fmaxf(fmaxf(v8[0], v8[1]), fmaxf(v8[2], v8[3])),
                         fmaxf(fmaxf(v8[4], v8[5]), fmaxf(v8[6], v8[7])));
        pm = fmaxf(pm, __shfl_xor(pm, 32));   // cross-half combine

        // ---- exact defer-rescale: only rescale when max grew
        if (!__all(pm <= m_run)) {
            float mn = fmaxf(m_run, pm);
            float scl = exp2f(m_run - mn);
            m_run = mn;
            l_run *= scl;
            acc0 *= scl;
            acc1 *= scl;
        }

#pragma unroll
        for (int r = 0; r < 16; ++r) s0[r] = exp2f(s0[r] - m_run);
#pragma unroll
        for (int r = 0; r < 16; ++r) s1[r] = exp2f(s1[r] - m_run);
        float a8[8];
#pragma unroll
        for (int r = 0; r < 8; ++r)
            a8[r] = (s0[r] + s0[r + 8]) + (s1[r] + s1[r + 8]);
        float rs = ((a8[0] + a8[1]) + (a8[2] + a8[3])) +
                   ((a8[4] + a8[5]) + (a8[6] + a8[7]));
        rs += __shfl_xor(rs, 32);             // cross-half combine
        l_run += rs;

        // ---- P exchange (permlane32_swap, distinct operands) + PV
        __builtin_amdgcn_s_setprio(1);
#pragma unroll
        for (int s = 0; s < 4; ++s) {
            const int base = 8 * (s & 1);
            f32x16& P = (s < 2) ? s0 : s1;
            u32 a0 = pack2(P[base + 0], P[base + 1]);
            u32 a1 = pack2(P[base + 2], P[base + 3]);
            u32 b0 = pack2(P[base + 4], P[base + 5]);
            u32 b1 = pack2(P[base + 6], P[base + 7]);
            // swap(a,b): a_high <-> b_low
            asm("v_permlane32_swap_b32 %0, %1" : "+v"(a0), "+v"(b0));
            asm("v_permlane32_swap_b32 %0, %1" : "+v"(a1), "+v"(b1));
            union { u32 u[4]; bf16x8 v; } pa;
            pa.u[0] = a0; pa.u[1] = a1; pa.u[2] = b0; pa.u[3] = b1;
            const bf16_t* vtb = VtB + cur * 4608;
            bf16x8 va0 = *(const bf16x8*)&vtb[l31 * 72 + s * 16 + hi * 8];
            bf16x8 va1 = *(const bf16x8*)&vtb[(32 + l31) * 72 + s * 16 + hi * 8];
            acc0 = __builtin_amdgcn_mfma_f32_32x32x16_bf16(va0, pa.v, acc0, 0, 0, 0);
            acc1 = __builtin_amdgcn_mfma_f32_32x32x16_bf16(va1, pa.v, acc1, 0, 0, 0);
        }
        __builtin_amdgcn_s_setprio(0);

        if (it + 1 < FNT) WRITE_V(cur ^ 1);
        __syncthreads();
    }

    // ---- epilogue
    bf16_t* sw = (bf16_t*)lds + wave * (32 * 72);
    float inv = 1.0f / l_run;
#pragma unroll
    for (int g = 0; g < 4; ++g) {
        bf16x4 w0, w1;
#pragma unroll
        for (int e = 0; e < 4; ++e) {
            w0[e] = (bf16_t)(acc0[4 * g + e] * inv);
            w1[e] = (bf16_t)(acc1[4 * g + e] * inv);
        }
        int d0 = 8 * g + 4 * hi;
        *(bf16x4*)&sw[l31 * 72 + d0] = w0;
        *(bf16x4*)&sw[l31 * 72 + 32 + d0] = w1;
    }
    __syncthreads();
    {
        int q = lane >> 1, half = lane & 1;
        const bf16_t* srow = sw + q * 72 + half * 32;
        int s = q0 + q;
        int b = bh >> 4, h = bh & 15;
        bf16_t* dst = AVb + ((size_t)s * BATCH + b) * DMODEL + h * HDIM + half * 32;
#pragma unroll
        for (int k = 0; k < 4; ++k)
            *(bf16x8*)(dst + k * 8) = *(const bf16x8*)(srow + k * 8);
    }
}

// ---------------------------------------------------------------------------
extern "C" void kernel_launch(void* const* d_in, const int* in_sizes, int n_in,
                              void* d_out, int out_size, void* d_ws, size_t ws_size,
                              hipStream_t stream)
{
    const float* X   = (const float*)d_in[0];
    const float* Wkv = (const float*)d_in[1];
    const float* bkv = (const float*)d_in[2];
    const float* Wq  = (const float*)d_in[3];
    const float* bq  = (const float*)d_in[4];
    const float* Wp  = (const float*)d_in[5];
    const float* bp  = (const float*)d_in[6];
    float* out = (float*)d_out;

    char* ws = (char*)d_ws;
    size_t off = 0;
    auto alloc = [&](size_t bytes) -> void* {
        void* p = ws + off;
        off += (bytes + 255) & ~(size_t)255;
        return p;
    };
    bf16_t* WqkvT = (bf16_t*)alloc((size_t)3072 * 1024 * 2);  // [Wkv^T ; Wq^T]
    bf16_t* WpT   = (bf16_t*)alloc((size_t)1024 * 1024 * 2);
    bf16_t* Qb    = (bf16_t*)alloc((size_t)32 * S_LEN * HDIM * 2);
    bf16_t* Kb    = (bf16_t*)alloc((size_t)32 * S_LEN * HDIM * 2);
    bf16_t* Vb    = (bf16_t*)alloc((size_t)32 * S_LEN * HDIM * 2);
    bf16_t* Xbf   = (bf16_t*)alloc((size_t)4096 * 1024 * 2);
    bf16_t* AVb   = (bf16_t*)alloc((size_t)4096 * 1024 * 2);

    xcvt_kernel<<<2048, 256, 0, stream>>>(X, Xbf);
    transpose_convert<<<dim3(32, 16), 256, 0, stream>>>(Wkv, WqkvT, 1024, 2048);
    transpose_convert<<<dim3(16, 16), 256, 0, stream>>>(
        Wq, WqkvT + (size_t)2048 * 1024, 1024, 1024);
    transpose_convert<<<dim3(16, 16), 256, 0, stream>>>(Wp, WpT, 1024, 1024);

    gemm_qkv<<<dim3(32, 24), 256, 0, stream>>>(Xbf, WqkvT, bkv, bq, Kb, Vb, Qb);
    flash_kernel<<<dim3(S_LEN / 128, 32), 256, 0, stream>>>(Qb, Kb, Vb, AVb);
    gemm_out_kernel<<<dim3(64, 8), 256, 0, stream>>>(AVb, WpT, bp, out);
}